// Round 4
// baseline (113.173 us; speedup 1.0000x reference)
//
#include <hip/hip_runtime.h>

// ContrastiveCosineLoss: mean over i<j of (cos_full(i,j) - cos_red(i,j))^2
// Fused as ONE GEMM: A_i = [fn_i, rn_i], B_j = [fn_j, -rn_j] (bf16, K=1152),
// diff_ij = dot(A_i, B_j); epilogue accumulates d^2 over upper triangle.
// 2 dispatches: norm (wave/row, zeroes ws slots) + pair_gemm (BK=128,
// 64-slot spread atomics + last-block finalize into d_out).

#define NROWS 2048
#define KFULL 1024
#define KRED  128
#define KTOT  1152
#define BK    128
#define BM    64
#define NT    (KTOT / BK)            // 9 K-tiles
#define NEG_T (KFULL / BK)           // tile 8 is the (negated) reduced block
#define TILES (NROWS / BM)           // 32
#define NBLK  (TILES * (TILES + 1) / 2)  // 528 upper-triangular blocks
#define LDT   136                    // padded LDS row stride (elems) -> 272 B
#define INV_PAIRS (1.0f / 2096128.0f)    // 1 / (N*(N-1)/2)
#define NSLOT 64                     // reduction slots, 128 B apart

typedef __attribute__((ext_vector_type(8))) short bf16x8;
typedef __attribute__((ext_vector_type(4))) float f32x4;

__device__ inline unsigned short f2bf(float f) {
  unsigned int u = __float_as_uint(f);
  u += 0x7FFFu + ((u >> 16) & 1u);   // round-to-nearest-even
  return (unsigned short)(u >> 16);
}

// ws layout: floats [0 .. 64*32) partial slots (stride 32 floats = 128 B),
// uint at float-index 2048 = done counter, A matrix at byte offset 16384.

// One WAVE per row: normalize full (1024) and reduced (128), write bf16 row.
__global__ __launch_bounds__(256) void norm_kernel(
    const float* __restrict__ red, const float* __restrict__ full,
    unsigned short* __restrict__ A, float* __restrict__ ws_part,
    unsigned int* __restrict__ ws_done)
{
  const int tid = threadIdx.x;
  if (blockIdx.x == 0) {             // zero reduction state for pair_gemm
    if (tid < NSLOT) ws_part[tid * 32] = 0.0f;
    if (tid == NSLOT) *ws_done = 0u;
  }
  const int lane = tid & 63;
  const int r = blockIdx.x * 4 + (tid >> 6);

  const float4* fr_ = (const float4*)(full + (size_t)r * KFULL);
  float4 v[4];
  #pragma unroll
  for (int c = 0; c < 4; ++c) v[c] = fr_[c * 64 + lane];
  const float2 u = ((const float2*)(red + (size_t)r * KRED))[lane];

  float ss = 0.f;
  #pragma unroll
  for (int c = 0; c < 4; ++c)
    ss += v[c].x * v[c].x + v[c].y * v[c].y + v[c].z * v[c].z + v[c].w * v[c].w;
  float ss2 = u.x * u.x + u.y * u.y;
  #pragma unroll
  for (int o = 1; o < 64; o <<= 1) {       // fused butterfly: all lanes get sums
    ss  += __shfl_xor(ss,  o, 64);
    ss2 += __shfl_xor(ss2, o, 64);
  }
  const float inv  = 1.0f / fmaxf(sqrtf(ss),  1e-8f);
  const float inv2 = 1.0f / fmaxf(sqrtf(ss2), 1e-8f);

  unsigned short* Ar = A + (size_t)r * KTOT;
  #pragma unroll
  for (int c = 0; c < 4; ++c) {
    ushort4 w;
    w.x = f2bf(v[c].x * inv); w.y = f2bf(v[c].y * inv);
    w.z = f2bf(v[c].z * inv); w.w = f2bf(v[c].w * inv);
    ((ushort4*)Ar)[c * 64 + lane] = w;
  }
  ushort2 w2;
  w2.x = f2bf(u.x * inv2); w2.y = f2bf(u.y * inv2);
  ((ushort2*)(Ar + KFULL))[lane] = w2;
}

// 64x64 tile per block, 4 waves (2x2), 2x2 MFMA 16x16x32 frags, BK=128.
__global__ __launch_bounds__(256) void pair_gemm(
    const unsigned short* __restrict__ A, float* __restrict__ ws_part,
    unsigned int* __restrict__ ws_done, float* __restrict__ out)
{
  __shared__ __align__(16) unsigned short ldsA[BM * LDT];
  __shared__ __align__(16) unsigned short ldsB[BM * LDT];
  __shared__ float redbuf[4];
  __shared__ int islast;

  const int tid = threadIdx.x;

  // linear block id -> upper-triangular (bi, bj), bi <= bj
  int rem = blockIdx.x;
  int bi = 0;
  while (rem >= TILES - bi) { rem -= TILES - bi; ++bi; }
  const int bj = bi + rem;

  // staging: thread t covers row = t>>2, elems (t&3)*32 .. +31 (4 x uint4)
  const int srow = tid >> 2;
  const int sk = (tid & 3) * 32;
  const unsigned short* pA = A + (size_t)(bi * BM + srow) * KTOT + sk;
  const unsigned short* pB = A + (size_t)(bj * BM + srow) * KTOT + sk;

  uint4 ra[4], rb[4];
  auto load_tile = [&](int t) {
    const int ko = t * BK;
    #pragma unroll
    for (int c = 0; c < 4; ++c) {
      ra[c] = *(const uint4*)(pA + ko + c * 8);
      rb[c] = *(const uint4*)(pB + ko + c * 8);
    }
    if (t >= NEG_T) {  // reduced block: B = -A (bf16 sign-bit flip)
      #pragma unroll
      for (int c = 0; c < 4; ++c) {
        rb[c].x ^= 0x80008000u; rb[c].y ^= 0x80008000u;
        rb[c].z ^= 0x80008000u; rb[c].w ^= 0x80008000u;
      }
    }
  };
  load_tile(0);

  const int lane = tid & 63;
  const int wv = tid >> 6;
  const int wr = wv >> 1, wc = wv & 1;
  const int fr = lane & 15;         // frag row (A) / col (B)
  const int fk = (lane >> 4) * 8;   // frag k-offset within 32

  f32x4 acc[2][2];
  #pragma unroll
  for (int m = 0; m < 2; ++m)
    #pragma unroll
    for (int n = 0; n < 2; ++n)
      acc[m][n] = (f32x4){0.f, 0.f, 0.f, 0.f};

  for (int t = 0; t < NT; ++t) {
    __syncthreads();  // previous tile's ds_reads complete
    #pragma unroll
    for (int c = 0; c < 4; ++c) {
      *(uint4*)&ldsA[srow * LDT + sk + c * 8] = ra[c];
      *(uint4*)&ldsB[srow * LDT + sk + c * 8] = rb[c];
    }
    __syncthreads();

    if (t + 1 < NT) load_tile(t + 1);  // prefetch: full BK=128 iter to land

    bf16x8 af[2][4], bf[2][4];
    #pragma unroll
    for (int kk = 0; kk < 4; ++kk) {
      #pragma unroll
      for (int m = 0; m < 2; ++m)
        af[m][kk] = *(const bf16x8*)&ldsA[(wr * 32 + m * 16 + fr) * LDT + kk * 32 + fk];
      #pragma unroll
      for (int n = 0; n < 2; ++n)
        bf[n][kk] = *(const bf16x8*)&ldsB[(wc * 32 + n * 16 + fr) * LDT + kk * 32 + fk];
    }
    #pragma unroll
    for (int kk = 0; kk < 4; ++kk)
      #pragma unroll
      for (int m = 0; m < 2; ++m)
        #pragma unroll
        for (int n = 0; n < 2; ++n)
          acc[m][n] = __builtin_amdgcn_mfma_f32_16x16x32_bf16(
              af[m][kk], bf[n][kk], acc[m][n], 0, 0, 0);
  }

  // epilogue: sum d^2 over strict upper triangle (gj > gi)
  float s = 0.f;
  #pragma unroll
  for (int m = 0; m < 2; ++m) {
    const int gi0 = bi * BM + wr * 32 + m * 16 + (lane >> 4) * 4;
    #pragma unroll
    for (int n = 0; n < 2; ++n) {
      const int gj = bj * BM + wc * 32 + n * 16 + fr;
      #pragma unroll
      for (int j = 0; j < 4; ++j) {
        if (gj > gi0 + j) {
          const float d = acc[m][n][j];
          s += d * d;
        }
      }
    }
  }
  #pragma unroll
  for (int o = 32; o > 0; o >>= 1) s += __shfl_down(s, o, 64);
  if (lane == 0) redbuf[wv] = s;
  __syncthreads();

  if (tid == 0) {
    const float tot = redbuf[0] + redbuf[1] + redbuf[2] + redbuf[3];
    atomicAdd(&ws_part[(blockIdx.x & (NSLOT - 1)) * 32], tot);  // 64 lines, low contention
    __threadfence();                                            // release slots
    const unsigned int old = atomicAdd(ws_done, 1u);
    islast = (old == NBLK - 1) ? 1 : 0;
  }
  __syncthreads();

  if (islast && tid < NSLOT) {       // last block finalizes: no extra dispatch
    float v = atomicAdd(&ws_part[tid * 32], 0.0f);   // coherent (device-scope) read
    #pragma unroll
    for (int o = 32; o > 0; o >>= 1) v += __shfl_down(v, o, 64);
    if (tid == 0) out[0] = v * INV_PAIRS;
  }
}

extern "C" void kernel_launch(void* const* d_in, const int* in_sizes, int n_in,
                              void* d_out, int out_size, void* d_ws, size_t ws_size,
                              hipStream_t stream)
{
  const float* red  = (const float*)d_in[0];   // (2048, 128) f32
  const float* full = (const float*)d_in[1];   // (2048, 1024) f32
  float* ws_part = (float*)d_ws;
  unsigned int* ws_done = (unsigned int*)d_ws + 2048;
  unsigned short* A = (unsigned short*)((char*)d_ws + 16384);  // 2048*1152 bf16

  norm_kernel<<<NROWS / 4, 256, 0, stream>>>(red, full, A, ws_part, ws_done);
  pair_gemm<<<NBLK, 256, 0, stream>>>(A, ws_part, ws_done, (float*)d_out);
}

// Round 5
// 82.398 us; speedup vs baseline: 1.3735x; 1.3735x over previous
//
#include <hip/hip_runtime.h>

// ContrastiveCosineLoss: mean over i<j of (cos_full(i,j) - cos_red(i,j))^2
// ONE GEMM: A_i = [fn_i, rn_i], B_j = [fn_j, -rn_j] (bf16, K=1152).
// v3: 128x128 tiles (136 upper-tri blocks, HALF the panel re-fetch traffic of
// 64x64), 8 waves/block, double-buffered XOR-swizzled LDS (1 barrier/iter),
// XCD-bijective block swizzle (136 = 8*17) for A-panel L2 residency.

#define NROWS 2048
#define KFULL 1024
#define KRED  128
#define KTOT  1152
#define BK    64
#define TM    128                    // tile dim
#define NT    (KTOT / BK)            // 18 K-tiles
#define NEG_T (KFULL / BK)           // tiles >= 16: negated reduced block
#define TILES (NROWS / TM)           // 16
#define NBLK  (TILES * (TILES + 1) / 2)  // 136
#define PANEL (TM * BK)              // 8192 elems = 16 KB
#define INV_PAIRS (1.0f / 2096128.0f)
#define NSLOT 64

typedef __attribute__((ext_vector_type(8))) short bf16x8;
typedef __attribute__((ext_vector_type(4))) float f32x4;

__device__ inline unsigned short f2bf(float f) {
  unsigned int u = __float_as_uint(f);
  u += 0x7FFFu + ((u >> 16) & 1u);   // round-to-nearest-even
  return (unsigned short)(u >> 16);
}

// ws layout: floats [0 .. 64*32) partial slots (128 B apart), uint at float
// index 2048 = done counter, A matrix at byte offset 16384.

// One WAVE per row: normalize full (1024) and reduced (128), write bf16 row.
__global__ __launch_bounds__(256) void norm_kernel(
    const float* __restrict__ red, const float* __restrict__ full,
    unsigned short* __restrict__ A, float* __restrict__ ws_part,
    unsigned int* __restrict__ ws_done)
{
  const int tid = threadIdx.x;
  if (blockIdx.x == 0) {             // zero reduction state for pair_gemm
    if (tid < NSLOT) ws_part[tid * 32] = 0.0f;
    if (tid == NSLOT) *ws_done = 0u;
  }
  const int lane = tid & 63;
  const int r = blockIdx.x * 4 + (tid >> 6);

  const float4* fr_ = (const float4*)(full + (size_t)r * KFULL);
  float4 v[4];
  #pragma unroll
  for (int c = 0; c < 4; ++c) v[c] = fr_[c * 64 + lane];
  const float2 u = ((const float2*)(red + (size_t)r * KRED))[lane];

  float ss = 0.f;
  #pragma unroll
  for (int c = 0; c < 4; ++c)
    ss += v[c].x * v[c].x + v[c].y * v[c].y + v[c].z * v[c].z + v[c].w * v[c].w;
  float ss2 = u.x * u.x + u.y * u.y;
  #pragma unroll
  for (int o = 1; o < 64; o <<= 1) {       // fused butterfly reduce
    ss  += __shfl_xor(ss,  o, 64);
    ss2 += __shfl_xor(ss2, o, 64);
  }
  const float inv  = 1.0f / fmaxf(sqrtf(ss),  1e-8f);
  const float inv2 = 1.0f / fmaxf(sqrtf(ss2), 1e-8f);

  unsigned short* Ar = A + (size_t)r * KTOT;
  #pragma unroll
  for (int c = 0; c < 4; ++c) {
    ushort4 w;
    w.x = f2bf(v[c].x * inv); w.y = f2bf(v[c].y * inv);
    w.z = f2bf(v[c].z * inv); w.w = f2bf(v[c].w * inv);
    ((ushort4*)Ar)[c * 64 + lane] = w;
  }
  ushort2 w2;
  w2.x = f2bf(u.x * inv2); w2.y = f2bf(u.y * inv2);
  ((ushort2*)(Ar + KFULL))[lane] = w2;
}

// 128x128 tile, 8 waves (2x4), wave tile 64x32 (4x2 frags of 16x16x32).
__global__ __launch_bounds__(512) void pair_gemm(
    const unsigned short* __restrict__ A, float* __restrict__ ws_part,
    unsigned int* __restrict__ ws_done, float* __restrict__ out)
{
  // lds[0..1] = A double-buffer, lds[2..3] = B double-buffer. 64 KB.
  __shared__ __align__(16) unsigned short lds[4][PANEL];
  __shared__ float redbuf[8];
  __shared__ int islast;

  const int tid = threadIdx.x;

  // XCD-bijective swizzle (136 = 8 XCDs * 17): consecutive swz ids (same
  // tile-row -> shared A panel) land on the same XCD's L2.
  const int swz = (blockIdx.x & 7) * 17 + (blockIdx.x >> 3);
  int rem = swz, bi = 0;
  while (rem >= TILES - bi) { rem -= TILES - bi; ++bi; }
  const int bj = bi + rem;

  // staging: thread t covers (row = t>>3, slot = t&7) for rows 0-63 (c=0)
  // and rows 64-127 (c=1); 16 B per (row,slot).
  const int sr0 = tid >> 3;          // 0..63
  const int ss  = tid & 7;           // 16B slot within 128B row
  const unsigned short* pA = A + (size_t)(bi * TM + sr0) * KTOT + ss * 8;
  const unsigned short* pB = A + (size_t)(bj * TM + sr0) * KTOT + ss * 8;
  const int sw0 = sr0 * 64 + ((ss ^ (sr0 & 7)) << 3);          // XOR-swizzled
  const int sw1 = (sr0 + 64) * 64 + ((ss ^ (sr0 & 7)) << 3);   // (row&7 same)

  uint4 ra0, ra1, rb0, rb1;
  auto load_regs = [&](int t) {
    const size_t ko = (size_t)t * BK;
    ra0 = *(const uint4*)(pA + ko);
    ra1 = *(const uint4*)(pA + ko + (size_t)64 * KTOT);
    rb0 = *(const uint4*)(pB + ko);
    rb1 = *(const uint4*)(pB + ko + (size_t)64 * KTOT);
    if (t >= NEG_T) {  // reduced block: B = -A (bf16 sign-bit flip)
      rb0.x ^= 0x80008000u; rb0.y ^= 0x80008000u; rb0.z ^= 0x80008000u; rb0.w ^= 0x80008000u;
      rb1.x ^= 0x80008000u; rb1.y ^= 0x80008000u; rb1.z ^= 0x80008000u; rb1.w ^= 0x80008000u;
    }
  };
  auto store_lds = [&](int b) {
    *(uint4*)&lds[b][sw0]     = ra0;
    *(uint4*)&lds[b][sw1]     = ra1;
    *(uint4*)&lds[2 + b][sw0] = rb0;
    *(uint4*)&lds[2 + b][sw1] = rb1;
  };

  const int lane = tid & 63;
  const int wv = tid >> 6;           // 0..7
  const int wr = wv >> 2;            // 0..1 : row half (64 rows)
  const int wc = wv & 3;             // 0..3 : col quarter (32 cols)
  const int fr = lane & 15;
  const int fs = lane >> 4;          // 0..3 : 16B slot quarter
  const int rx = fr & 7;             // row&7 for swizzle (frag rows = base+fr)

  f32x4 acc[4][2];
  #pragma unroll
  for (int m = 0; m < 4; ++m)
    #pragma unroll
    for (int n = 0; n < 2; ++n)
      acc[m][n] = (f32x4){0.f, 0.f, 0.f, 0.f};

  load_regs(0);
  store_lds(0);

  for (int t = 0; t < NT; ++t) {
    __syncthreads();                 // buf[t&1] staged & prior reads done
    const bool pf = (t + 1 < NT);
    if (pf) load_regs(t + 1);        // issue early: lands under compute

    const int b = t & 1;
    #pragma unroll
    for (int kk = 0; kk < 2; ++kk) {
      const int sl = ((kk * 4 + fs) ^ rx) << 3;   // swizzled 16B slot
      bf16x8 af[4], bf[2];
      #pragma unroll
      for (int m = 0; m < 4; ++m)
        af[m] = *(const bf16x8*)&lds[b][(wr * 64 + m * 16 + fr) * 64 + sl];
      #pragma unroll
      for (int n = 0; n < 2; ++n)
        bf[n] = *(const bf16x8*)&lds[2 + b][(wc * 32 + n * 16 + fr) * 64 + sl];
      #pragma unroll
      for (int m = 0; m < 4; ++m)
        #pragma unroll
        for (int n = 0; n < 2; ++n)
          acc[m][n] = __builtin_amdgcn_mfma_f32_16x16x32_bf16(
              af[m], bf[n], acc[m][n], 0, 0, 0);
    }
    if (pf) store_lds((t + 1) & 1);  // other buffer: no barrier needed here
  }

  // epilogue: sum d^2 over strict upper triangle (gj > gi)
  float s = 0.f;
  #pragma unroll
  for (int m = 0; m < 4; ++m) {
    const int gi0 = bi * TM + wr * 64 + m * 16 + (lane >> 4) * 4;
    #pragma unroll
    for (int n = 0; n < 2; ++n) {
      const int gj = bj * TM + wc * 32 + n * 16 + fr;
      #pragma unroll
      for (int j = 0; j < 4; ++j) {
        if (gj > gi0 + j) {
          const float d = acc[m][n][j];
          s += d * d;
        }
      }
    }
  }
  #pragma unroll
  for (int o = 32; o > 0; o >>= 1) s += __shfl_down(s, o, 64);
  if (lane == 0) redbuf[wv] = s;
  __syncthreads();

  if (tid == 0) {
    float tot = 0.f;
    #pragma unroll
    for (int w = 0; w < 8; ++w) tot += redbuf[w];
    atomicAdd(&ws_part[(blockIdx.x & (NSLOT - 1)) * 32], tot);
    __threadfence();                                 // release slots
    const unsigned int old = atomicAdd(ws_done, 1u);
    islast = (old == NBLK - 1) ? 1 : 0;
  }
  __syncthreads();

  if (islast && tid < NSLOT) {       // last block finalizes (no extra dispatch)
    float v = atomicAdd(&ws_part[tid * 32], 0.0f);   // device-scope read
    #pragma unroll
    for (int o = 32; o > 0; o >>= 1) v += __shfl_down(v, o, 64);
    if (tid == 0) out[0] = v * INV_PAIRS;
  }
}

extern "C" void kernel_launch(void* const* d_in, const int* in_sizes, int n_in,
                              void* d_out, int out_size, void* d_ws, size_t ws_size,
                              hipStream_t stream)
{
  const float* red  = (const float*)d_in[0];   // (2048, 128) f32
  const float* full = (const float*)d_in[1];   // (2048, 1024) f32
  float* ws_part = (float*)d_ws;
  unsigned int* ws_done = (unsigned int*)d_ws + 2048;
  unsigned short* A = (unsigned short*)((char*)d_ws + 16384);  // 2048x1152 bf16

  norm_kernel<<<NROWS / 4, 256, 0, stream>>>(red, full, A, ws_part, ws_done);
  pair_gemm<<<NBLK, 512, 0, stream>>>(A, ws_part, ws_done, (float*)d_out);
}

// Round 7
// 80.797 us; speedup vs baseline: 1.4007x; 1.0198x over previous
//
#include <hip/hip_runtime.h>

// ContrastiveCosineLoss: mean over i<j of (cos_full(i,j) - cos_red(i,j))^2
// ONE GEMM: A_i = [fn_i, rn_i], B_j = [fn_j, -rn_j] (bf16, K=1152).
// v4: 128x64 rectangular tiles -> 272 blocks (full 256-CU machine) while
// keeping panel traffic at 118 MB. Double-buffered XOR-swizzled LDS,
// 1 barrier/iter, XCD-bijective swizzle (272 = 8*34), fused d^2 epilogue,
// 64-slot spread atomics + last-block finalize.

#define NROWS 2048
#define KFULL 1024
#define KRED  128
#define KTOT  1152
#define BK    64
#define NT    (KTOT / BK)            // 18 K-tiles
#define NEG_T (KFULL / BK)           // tiles >= 16: negated reduced block
#define RT    16                     // row tiles (128 rows)
#define CT    32                     // col tiles (64 cols)
#define NBLK  272                    // sum over bi of (32 - 2*bi)
#define INV_PAIRS (1.0f / 2096128.0f)
#define NSLOT 64

typedef __attribute__((ext_vector_type(8))) short bf16x8;
typedef __attribute__((ext_vector_type(4))) float f32x4;

__device__ inline unsigned short f2bf(float f) {
  unsigned int u = __float_as_uint(f);
  u += 0x7FFFu + ((u >> 16) & 1u);   // round-to-nearest-even
  return (unsigned short)(u >> 16);
}

// ws layout: floats [0 .. 64*32) partial slots (128 B apart), uint at float
// index 2048 = done counter, A matrix at byte offset 16384.

// One WAVE per row: normalize full (1024) and reduced (128), write bf16 row.
__global__ __launch_bounds__(256) void norm_kernel(
    const float* __restrict__ red, const float* __restrict__ full,
    unsigned short* __restrict__ A, float* __restrict__ ws_part,
    unsigned int* __restrict__ ws_done)
{
  const int tid = threadIdx.x;
  if (blockIdx.x == 0) {             // zero reduction state for pair_gemm
    if (tid < NSLOT) ws_part[tid * 32] = 0.0f;
    if (tid == NSLOT) *ws_done = 0u;
  }
  const int lane = tid & 63;
  const int r = blockIdx.x * 4 + (tid >> 6);

  const float4* fr_ = (const float4*)(full + (size_t)r * KFULL);
  float4 v[4];
  #pragma unroll
  for (int c = 0; c < 4; ++c) v[c] = fr_[c * 64 + lane];
  const float2 u = ((const float2*)(red + (size_t)r * KRED))[lane];

  float ss = 0.f;
  #pragma unroll
  for (int c = 0; c < 4; ++c)
    ss += v[c].x * v[c].x + v[c].y * v[c].y + v[c].z * v[c].z + v[c].w * v[c].w;
  float ss2 = u.x * u.x + u.y * u.y;
  #pragma unroll
  for (int o = 1; o < 64; o <<= 1) {       // fused butterfly reduce
    ss  += __shfl_xor(ss,  o, 64);
    ss2 += __shfl_xor(ss2, o, 64);
  }
  const float inv  = 1.0f / fmaxf(sqrtf(ss),  1e-8f);
  const float inv2 = 1.0f / fmaxf(sqrtf(ss2), 1e-8f);

  unsigned short* Ar = A + (size_t)r * KTOT;
  #pragma unroll
  for (int c = 0; c < 4; ++c) {
    ushort4 w;
    w.x = f2bf(v[c].x * inv); w.y = f2bf(v[c].y * inv);
    w.z = f2bf(v[c].z * inv); w.w = f2bf(v[c].w * inv);
    ((ushort4*)Ar)[c * 64 + lane] = w;
  }
  ushort2 w2;
  w2.x = f2bf(u.x * inv2); w2.y = f2bf(u.y * inv2);
  ((ushort2*)(Ar + KFULL))[lane] = w2;
}

// 128x64 tile, 8 waves (4x2), wave tile 32x32 (2x2 frags of 16x16x32).
__global__ __launch_bounds__(512) void pair_gemm(
    const unsigned short* __restrict__ A, float* __restrict__ ws_part,
    unsigned int* __restrict__ ws_done, float* __restrict__ out)
{
  __shared__ __align__(16) unsigned short ldsA[2][128 * 64];  // 32 KB
  __shared__ __align__(16) unsigned short ldsB[2][64 * 64];   // 16 KB
  __shared__ float redbuf[8];
  __shared__ int islast;

  const int tid = threadIdx.x;

  // XCD-bijective swizzle (272 = 8 XCDs * 34): each XCD gets 34 consecutive
  // tile ids -> 1-2 row-panels resident in its L2.
  const int swz = (blockIdx.x & 7) * 34 + (blockIdx.x >> 3);
  int rem = swz, bi = 0;
  while (rem >= CT - 2 * bi) { rem -= CT - 2 * bi; ++bi; }
  const int bj = 2 * bi + rem;       // 2*bi .. 31

  // staging: thread t -> (row = t>>3, 16B slot = t&7); A covers rows sr and
  // sr+64 (two loads), B covers row sr (one load).
  const int sr = tid >> 3;           // 0..63
  const int ss = tid & 7;
  const unsigned short* pA = A + (size_t)(bi * 128 + sr) * KTOT + ss * 8;
  const unsigned short* pB = A + (size_t)(bj * 64 + sr) * KTOT + ss * 8;
  const int swA0 = sr * 64 + ((ss ^ (sr & 7)) << 3);          // XOR-swizzled
  const int swA1 = (sr + 64) * 64 + ((ss ^ (sr & 7)) << 3);   // same row&7
  const int swB  = sr * 64 + ((ss ^ (sr & 7)) << 3);

  uint4 ra0, ra1, rb;
  auto load_regs = [&](int t) {
    const size_t ko = (size_t)t * BK;
    ra0 = *(const uint4*)(pA + ko);
    ra1 = *(const uint4*)(pA + ko + (size_t)64 * KTOT);
    rb  = *(const uint4*)(pB + ko);
    if (t >= NEG_T) {  // reduced block: B = -A (bf16 sign-bit flip)
      rb.x ^= 0x80008000u; rb.y ^= 0x80008000u;
      rb.z ^= 0x80008000u; rb.w ^= 0x80008000u;
    }
  };
  auto store_lds = [&](int b) {
    *(uint4*)&ldsA[b][swA0] = ra0;
    *(uint4*)&ldsA[b][swA1] = ra1;
    *(uint4*)&ldsB[b][swB]  = rb;
  };

  const int lane = tid & 63;
  const int wv = tid >> 6;           // 0..7
  const int wr = wv >> 1;            // 0..3 : 32-row band
  const int wc = wv & 1;             // 0..1 : 32-col band
  const int fr = lane & 15;
  const int fs = lane >> 4;          // 0..3
  const int rx = fr & 7;             // swizzle key of frag rows

  f32x4 acc[2][2];
  #pragma unroll
  for (int m = 0; m < 2; ++m)
    #pragma unroll
    for (int n = 0; n < 2; ++n)
      acc[m][n] = (f32x4){0.f, 0.f, 0.f, 0.f};

  load_regs(0);
  store_lds(0);

  for (int t = 0; t < NT; ++t) {
    __syncthreads();                 // buf[t&1] staged & prior reads done
    const bool pf = (t + 1 < NT);
    if (pf) load_regs(t + 1);        // issue early: lands under compute

    const int b = t & 1;
    #pragma unroll
    for (int kk = 0; kk < 2; ++kk) {
      const int sl = ((kk * 4 + fs) ^ rx) << 3;   // swizzled 16B slot
      bf16x8 af[2], bf[2];
      #pragma unroll
      for (int m = 0; m < 2; ++m)
        af[m] = *(const bf16x8*)&ldsA[b][(wr * 32 + m * 16 + fr) * 64 + sl];
      #pragma unroll
      for (int n = 0; n < 2; ++n)
        bf[n] = *(const bf16x8*)&ldsB[b][(wc * 32 + n * 16 + fr) * 64 + sl];
      #pragma unroll
      for (int m = 0; m < 2; ++m)
        #pragma unroll
        for (int n = 0; n < 2; ++n)
          acc[m][n] = __builtin_amdgcn_mfma_f32_16x16x32_bf16(
              af[m], bf[n], acc[m][n], 0, 0, 0);
    }
    if (pf) store_lds((t + 1) & 1);  // other buffer: safe without barrier
  }

  // epilogue: sum d^2 over strict upper triangle (gj > gi)
  float s = 0.f;
  #pragma unroll
  for (int m = 0; m < 2; ++m) {
    const int gi0 = bi * 128 + wr * 32 + m * 16 + fs * 4;
    #pragma unroll
    for (int n = 0; n < 2; ++n) {
      const int gj = bj * 64 + wc * 32 + n * 16 + fr;
      #pragma unroll
      for (int j = 0; j < 4; ++j) {
        if (gj > gi0 + j) {
          const float d = acc[m][n][j];
          s += d * d;
        }
      }
    }
  }
  #pragma unroll
  for (int o = 32; o > 0; o >>= 1) s += __shfl_down(s, o, 64);
  if (lane == 0) redbuf[wv] = s;
  __syncthreads();

  if (tid == 0) {
    float tot = 0.f;
    #pragma unroll
    for (int w = 0; w < 8; ++w) tot += redbuf[w];
    atomicAdd(&ws_part[(blockIdx.x & (NSLOT - 1)) * 32], tot);
    __threadfence();                                 // release slots
    const unsigned int old = atomicAdd(ws_done, 1u);
    islast = (old == NBLK - 1) ? 1 : 0;
  }
  __syncthreads();

  if (islast && tid < NSLOT) {       // last block finalizes (no extra dispatch)
    float v = atomicAdd(&ws_part[tid * 32], 0.0f);   // device-scope read
    #pragma unroll
    for (int o = 32; o > 0; o >>= 1) v += __shfl_down(v, o, 64);
    if (tid == 0) out[0] = v * INV_PAIRS;
  }
}

extern "C" void kernel_launch(void* const* d_in, const int* in_sizes, int n_in,
                              void* d_out, int out_size, void* d_ws, size_t ws_size,
                              hipStream_t stream)
{
  const float* red  = (const float*)d_in[0];   // (2048, 128) f32
  const float* full = (const float*)d_in[1];   // (2048, 1024) f32
  float* ws_part = (float*)d_ws;
  unsigned int* ws_done = (unsigned int*)d_ws + 2048;
  unsigned short* A = (unsigned short*)((char*)d_ws + 16384);  // 2048x1152 bf16

  norm_kernel<<<NROWS / 4, 256, 0, stream>>>(red, full, A, ws_part, ws_done);
  pair_gemm<<<NBLK, 512, 0, stream>>>(A, ws_part, ws_done, (float*)d_out);
}